// Round 13
// baseline (470.040 us; speedup 1.0000x reference)
//
#include <hip/hip_runtime.h>
#include <hip/hip_bf16.h>
#include <hip/hip_fp16.h>

// NeuralNetwork_85255100825763
// conv1+bn+relu+pool -> conv2+bn+relu+pool -> MLP+softmax gate
// -> 8x LSTM(128) over 256 steps -> gated mean -> output proj.
//
// LSTM v13 (MFMA + weights in FIXED PHYSICAL AGPRs): R0-R12 proved the
// compiler reloads loop-invariant weight registers every iteration no
// matter what (grants 48-88 arch-VGPRs; pins/attributes all ignored),
// costing ~2000cy/step of scratch/L2 traffic. v13 writes the 16 weight
// quads into hard-coded a0-a63 via v_accvgpr_write (one-time prologue asm)
// and issues the 16 MFMAs from inline asm reading a[0:3]..a[60:63] as the
// A-operand (gfx950: MFMA A can be AGPR; B/C/D stay compiler-"v"). After
// the writes the C++ weight values are dead -> nothing to spill; visible
// pressure ~75 < 88 grant -> compiler never touches AGPRs.
// Geometry = R10 (numerically verified): 8 waves/block, wave owns j-tile,
// all 4 gate types, thread-local cell update, swizzled fp16 h-LDS,
// packed (bias,xw) dot2 epilogue.

typedef _Float16 h2_t  __attribute__((ext_vector_type(2)));
typedef float    f32x4 __attribute__((ext_vector_type(4)));
typedef unsigned int u32x2 __attribute__((ext_vector_type(2)));
typedef unsigned int u32x4 __attribute__((ext_vector_type(4)));

__device__ __forceinline__ float dot2f(unsigned int w, unsigned int h, float acc) {
    return __builtin_amdgcn_fdot2(__builtin_bit_cast(h2_t, w),
                                  __builtin_bit_cast(h2_t, h), acc, false);
}
__device__ __forceinline__ float sigmoidf_(float x) {
    return 1.0f / (1.0f + __expf(-x));
}
__device__ __forceinline__ float tanhf_(float x) {
    float t = __expf(-2.0f * fabsf(x));   // in (0,1], no overflow
    float r = (1.0f - t) / (1.0f + t);
    return copysignf(r, x);
}
__device__ __forceinline__ unsigned short f2h(float x) {
    __half h = __float2half(x);           // RTNE
    return *(unsigned short*)&h;
}

// ---------------- Kernel 0a: whh fp32 -> packed fp16 pairs (uint)
__global__ __launch_bounds__(256) void k_cvt(
    const float* __restrict__ w, unsigned int* __restrict__ wh)
{
    int i = blockIdx.x * 256 + threadIdx.x;     // 262144 pairs
    float2 f = ((const float2*)w)[i];
    wh[i] = (unsigned int)f2h(f.x) | ((unsigned int)f2h(f.y) << 16);
}

// ---------------- Kernel 0b: packed (bias, xw) fp16 per gate row
__global__ __launch_bounds__(256) void k_bx(
    const float* __restrict__ wih, const float* __restrict__ bih,
    const float* __restrict__ bhh, unsigned int* __restrict__ bx)
{
    int i = blockIdx.x * 256 + threadIdx.x;     // 4096 = 8*512
    float bias = bih[i] + bhh[i];
    bx[i] = (unsigned int)f2h(bias) | ((unsigned int)f2h(wih[i]) << 16);
}

// ---------------- Kernel 1: conv1 + bn1 + relu + maxpool2 -> c1 (64,16,64,64)
__global__ __launch_bounds__(256) void k_conv1(
    const float* __restrict__ x, const float* __restrict__ w,
    const float* __restrict__ cb, const float* __restrict__ g,
    const float* __restrict__ bb, const float* __restrict__ m,
    const float* __restrict__ v, float* __restrict__ c1)
{
    __shared__ __align__(16) float w1s[192];
    __shared__ float As[16], Cs[16];
    int tid = threadIdx.x;
    if (tid < 192) w1s[tid] = w[tid];
    if (tid < 16) {
        float s = g[tid] / sqrtf(v[tid] + 1e-5f);
        As[tid] = s;
        Cs[tid] = (cb[tid] - m[tid]) * s + bb[tid];
    }
    __syncthreads();

    int gid = blockIdx.x * 256 + tid;
    int b   = gid >> 12;
    int rem = gid & 4095;
    int oi  = rem >> 6, oj = rem & 63;

    float xr[3][4][4];
    #pragma unroll
    for (int ci = 0; ci < 3; ++ci) {
        #pragma unroll
        for (int r = 0; r < 4; ++r) {
            const float4 t4 = *(const float4*)(x +
                (((size_t)(b * 3 + ci) * 256 + (4 * oi + r)) * 256 + 4 * oj));
            xr[ci][r][0] = t4.x; xr[ci][r][1] = t4.y;
            xr[ci][r][2] = t4.z; xr[ci][r][3] = t4.w;
        }
    }
    const float4* w4 = (const float4*)w1s;
    #pragma unroll
    for (int co = 0; co < 16; ++co) {
        float val[2][2] = {{0.f, 0.f}, {0.f, 0.f}};
        #pragma unroll
        for (int ci = 0; ci < 3; ++ci) {
            float4 wq = w4[co * 3 + ci];
            #pragma unroll
            for (int pi = 0; pi < 2; ++pi) {
                #pragma unroll
                for (int pj = 0; pj < 2; ++pj) {
                    float a = val[pi][pj];
                    a = fmaf(xr[ci][2*pi  ][2*pj  ], wq.x, a);
                    a = fmaf(xr[ci][2*pi  ][2*pj+1], wq.y, a);
                    a = fmaf(xr[ci][2*pi+1][2*pj  ], wq.z, a);
                    a = fmaf(xr[ci][2*pi+1][2*pj+1], wq.w, a);
                    val[pi][pj] = a;
                }
            }
        }
        float A = As[co], C = Cs[co];
        float mx = 0.0f;
        #pragma unroll
        for (int pi = 0; pi < 2; ++pi)
            #pragma unroll
            for (int pj = 0; pj < 2; ++pj)
                mx = fmaxf(mx, fmaf(A, val[pi][pj], C));
        c1[((size_t)(b * 16 + co) * 64 + oi) * 64 + oj] = mx;
    }
}

// ---------------- Kernel 2: conv2 + bn2 + relu + maxpool2 -> c (64,256)
__global__ __launch_bounds__(256) void k_conv2(
    const float* __restrict__ c1, const float* __restrict__ w2,
    const float* __restrict__ cb, const float* __restrict__ g,
    const float* __restrict__ bb, const float* __restrict__ m,
    const float* __restrict__ v, float* __restrict__ c)
{
    __shared__ float w2s[64];
    int tid = threadIdx.x;
    if (tid < 64) w2s[tid] = w2[tid];
    __syncthreads();
    float A2 = g[0] / sqrtf(v[0] + 1e-5f);
    float C2 = (cb[0] - m[0]) * A2 + bb[0];

    int gid = blockIdx.x * 256 + tid;
    int b   = gid >> 8;
    int rem = gid & 255;
    int oi  = rem >> 4, oj = rem & 15;

    float val[2][2] = {{0.f, 0.f}, {0.f, 0.f}};
    for (int ci = 0; ci < 16; ++ci) {
        float xr[4][4];
        #pragma unroll
        for (int r = 0; r < 4; ++r) {
            float4 t4 = *(const float4*)(c1 +
                (((size_t)(b * 16 + ci) * 64 + (4 * oi + r)) * 64 + 4 * oj));
            xr[r][0] = t4.x; xr[r][1] = t4.y; xr[r][2] = t4.z; xr[r][3] = t4.w;
        }
        float w0 = w2s[ci*4+0], w1 = w2s[ci*4+1], w2v = w2s[ci*4+2], w3 = w2s[ci*4+3];
        #pragma unroll
        for (int pi = 0; pi < 2; ++pi) {
            #pragma unroll
            for (int pj = 0; pj < 2; ++pj) {
                float a = val[pi][pj];
                a = fmaf(xr[2*pi  ][2*pj  ], w0, a);
                a = fmaf(xr[2*pi  ][2*pj+1], w1, a);
                a = fmaf(xr[2*pi+1][2*pj  ], w2v, a);
                a = fmaf(xr[2*pi+1][2*pj+1], w3, a);
                val[pi][pj] = a;
            }
        }
    }
    float mx = 0.0f;
    #pragma unroll
    for (int pi = 0; pi < 2; ++pi)
        #pragma unroll
        for (int pj = 0; pj < 2; ++pj)
            mx = fmaxf(mx, fmaf(A2, val[pi][pj], C2));
    c[(size_t)b * 256 + oi * 16 + oj] = mx;
}

// ---------------- Kernel 3: MLP + softmax -> S (64,8) row-major flat
__global__ __launch_bounds__(64) void k_mlp(
    const float* __restrict__ c,
    const float* __restrict__ w1, const float* __restrict__ b1,
    const float* __restrict__ w2, const float* __restrict__ b2,
    const float* __restrict__ w3, const float* __restrict__ b3,
    float* __restrict__ S)
{
    __shared__ __align__(16) float cs[256];
    __shared__ float h1s[32], h2s[32], ls[8];
    int b = blockIdx.x, tid = threadIdx.x;
    *(float4*)&cs[tid * 4] = *(const float4*)(c + (size_t)b * 256 + tid * 4);
    __syncthreads();
    if (tid < 32) {
        float acc = b1[tid];
        for (int k = 0; k < 256; ++k) acc = fmaf(cs[k], w1[tid * 256 + k], acc);
        h1s[tid] = fmaxf(acc, 0.f);
    }
    __syncthreads();
    if (tid < 32) {
        float acc = b2[tid];
        #pragma unroll
        for (int k = 0; k < 32; ++k) acc = fmaf(h1s[k], w2[tid * 32 + k], acc);
        h2s[tid] = fmaxf(acc, 0.f);
    }
    __syncthreads();
    if (tid < 8) {
        float acc = b3[tid];
        #pragma unroll
        for (int k = 0; k < 32; ++k) acc = fmaf(h2s[k], w3[tid * 32 + k], acc);
        ls[tid] = acc;
    }
    __syncthreads();
    if (tid == 0) {
        float mx = ls[0];
        #pragma unroll
        for (int k = 1; k < 8; ++k) mx = fmaxf(mx, ls[k]);
        float e[8]; float sum = 0.f;
        #pragma unroll
        for (int k = 0; k < 8; ++k) { e[k] = expf(ls[k] - mx); sum += e[k]; }
        float inv = 1.0f / sum;
        #pragma unroll
        for (int k = 0; k < 8; ++k) S[b * 8 + k] = e[k] * inv;
    }
}

// write one u32x4 quad into AGPRs a<A0>..a<A0+3>
#define AWRITE4(Q, A0, A1, A2, A3)                                   \
    asm volatile("v_accvgpr_write_b32 " A0 ", %0\n\t"                \
                 "v_accvgpr_write_b32 " A1 ", %1\n\t"                \
                 "v_accvgpr_write_b32 " A2 ", %2\n\t"                \
                 "v_accvgpr_write_b32 " A3 ", %3"                    \
                 :: "v"(Q[0]), "v"(Q[1]), "v"(Q[2]), "v"(Q[3])       \
                 : A0, A1, A2, A3)

// ---------------- Kernel 4: LSTM via MFMA, weights in fixed AGPRs a0-a63.
// Block = (class, 16 batch rows), 512 threads = 8 waves.
// Wave q owns j-tile q (16 hidden dims), all 4 gate types; thread-local update.
__global__
__attribute__((amdgpu_flat_work_group_size(512, 512), amdgpu_waves_per_eu(2, 2)))
void k_lstm(
    const unsigned int* __restrict__ whh_h,  // fp16 pairs [8][512][64]
    const unsigned int* __restrict__ bx,     // packed (bias,xw) fp16 [8][512]
    const float* __restrict__ hn, const float* __restrict__ c,
    float* __restrict__ lasth)
{
    __shared__ __align__(16) unsigned short h_sw[2048];  // [16 n][128 k] fp16, byte^((n&7)<<4)
    __shared__ __align__(16) float c_l[4096];            // [256 t][16 n]

    int tid  = threadIdx.x;
    int wv   = tid >> 6, lane = tid & 63;    // wv = q = j-tile index 0..7
    int lrow = lane & 15, lgrp = lane >> 4;
    int kcls = blockIdx.x >> 2;
    int bbase = (blockIdx.x & 3) * 16;

    // ---- load 16 weight quads (transient) and park them in a0-a63 ----
    const unsigned int* wbase = whh_h + (size_t)kcls * 32768;
    int rI = (0*128 + wv*16 + lrow) * 64 + lgrp*4;
    int rF = (1*128 + wv*16 + lrow) * 64 + lgrp*4;
    int rG = (2*128 + wv*16 + lrow) * 64 + lgrp*4;
    int rO = (3*128 + wv*16 + lrow) * 64 + lgrp*4;
    {
        u32x4 q0, q1, q2, q3;
        q0 = *(const u32x4*)(wbase+rI+ 0); q1 = *(const u32x4*)(wbase+rI+16);
        q2 = *(const u32x4*)(wbase+rI+32); q3 = *(const u32x4*)(wbase+rI+48);
        AWRITE4(q0, "a0",  "a1",  "a2",  "a3");
        AWRITE4(q1, "a4",  "a5",  "a6",  "a7");
        AWRITE4(q2, "a8",  "a9",  "a10", "a11");
        AWRITE4(q3, "a12", "a13", "a14", "a15");
        q0 = *(const u32x4*)(wbase+rF+ 0); q1 = *(const u32x4*)(wbase+rF+16);
        q2 = *(const u32x4*)(wbase+rF+32); q3 = *(const u32x4*)(wbase+rF+48);
        AWRITE4(q0, "a16", "a17", "a18", "a19");
        AWRITE4(q1, "a20", "a21", "a22", "a23");
        AWRITE4(q2, "a24", "a25", "a26", "a27");
        AWRITE4(q3, "a28", "a29", "a30", "a31");
        q0 = *(const u32x4*)(wbase+rG+ 0); q1 = *(const u32x4*)(wbase+rG+16);
        q2 = *(const u32x4*)(wbase+rG+32); q3 = *(const u32x4*)(wbase+rG+48);
        AWRITE4(q0, "a32", "a33", "a34", "a35");
        AWRITE4(q1, "a36", "a37", "a38", "a39");
        AWRITE4(q2, "a40", "a41", "a42", "a43");
        AWRITE4(q3, "a44", "a45", "a46", "a47");
        q0 = *(const u32x4*)(wbase+rO+ 0); q1 = *(const u32x4*)(wbase+rO+16);
        q2 = *(const u32x4*)(wbase+rO+32); q3 = *(const u32x4*)(wbase+rO+48);
        AWRITE4(q0, "a48", "a49", "a50", "a51");
        AWRITE4(q1, "a52", "a53", "a54", "a55");
        AWRITE4(q2, "a56", "a57", "a58", "a59");
        AWRITE4(q3, "a60", "a61", "a62", "a63");
    }

    const unsigned int* bxp = bx + kcls * 512;
    u32x4 bxi = *(const u32x4*)(bxp + 0*128 + wv*16 + lgrp*4);
    u32x4 bxf = *(const u32x4*)(bxp + 1*128 + wv*16 + lgrp*4);
    u32x4 bxg = *(const u32x4*)(bxp + 2*128 + wv*16 + lgrp*4);
    u32x4 bxq = *(const u32x4*)(bxp + 3*128 + wv*16 + lgrp*4);

    #pragma unroll
    for (int i = 0; i < 2; ++i) {
        int idx = tid + i*512;
        int n = idx >> 6, j0 = (idx & 63) * 2;
        const float* hp = hn + ((size_t)kcls*64 + bbase + n)*128 + j0;
        unsigned int pk = (unsigned int)f2h(hp[0]) | ((unsigned int)f2h(hp[1]) << 16);
        *(unsigned int*)((char*)h_sw + ((n*256 + j0*2) ^ ((n & 7) << 4))) = pk;
    }
    #pragma unroll
    for (int i = 0; i < 8; ++i) {
        int idx = tid + i*512;
        int n = idx >> 8, t = idx & 255;
        c_l[t*16 + n] = c[(size_t)(bbase + n)*256 + t];
    }
    float cc0 = 0.f, cc1 = 0.f, cc2 = 0.f, cc3 = 0.f;
    __syncthreads();

    int  swz = (lrow & 7) << 4;
    int  hb  = lrow*256 + lgrp*16;
    int  hw  = (lrow*256 + (wv*16 + lgrp*4)*2) ^ swz;
    bool dolast = (wv == 7) && (lgrp == 3);         // owns j=127 (r=3)
    float* lastp = lasth + ((size_t)kcls*64 + bbase + lrow)*256;

#define CELL(R, CC, HV)                                         \
    {                                                           \
        float gi = sigmoidf_(dot2f(bxi[R], pk2, di[R]));        \
        float gf = sigmoidf_(dot2f(bxf[R], pk2, df2[R]));       \
        float gg = tanhf_   (dot2f(bxg[R], pk2, dg[R]));        \
        float go = sigmoidf_(dot2f(bxq[R], pk2, dq[R]));        \
        CC = gf * CC + gi * gg;                                 \
        HV = go * tanhf_(CC);                                   \
    }

    for (int t = 0; t < 256; ++t) {
        u32x4 b0 = *(const u32x4*)((char*)h_sw + ((hb +   0) ^ swz));
        u32x4 b1 = *(const u32x4*)((char*)h_sw + ((hb +  64) ^ swz));
        u32x4 b2 = *(const u32x4*)((char*)h_sw + ((hb + 128) ^ swz));
        u32x4 b3 = *(const u32x4*)((char*)h_sw + ((hb + 192) ^ swz));
        f32x4 di  = {0.f,0.f,0.f,0.f}, df2 = {0.f,0.f,0.f,0.f};
        f32x4 dg  = {0.f,0.f,0.f,0.f}, dq  = {0.f,0.f,0.f,0.f};
        // 16 MFMAs: A from fixed AGPRs, B/C/D in compiler VGPRs.
        asm volatile(
            "s_nop 3\n\t"
            "v_mfma_f32_16x16x32_f16 %0, a[0:3],   %4, %0\n\t"
            "v_mfma_f32_16x16x32_f16 %1, a[16:19], %4, %1\n\t"
            "v_mfma_f32_16x16x32_f16 %2, a[32:35], %4, %2\n\t"
            "v_mfma_f32_16x16x32_f16 %3, a[48:51], %4, %3\n\t"
            "v_mfma_f32_16x16x32_f16 %0, a[4:7],   %5, %0\n\t"
            "v_mfma_f32_16x16x32_f16 %1, a[20:23], %5, %1\n\t"
            "v_mfma_f32_16x16x32_f16 %2, a[36:39], %5, %2\n\t"
            "v_mfma_f32_16x16x32_f16 %3, a[52:55], %5, %3\n\t"
            "v_mfma_f32_16x16x32_f16 %0, a[8:11],  %6, %0\n\t"
            "v_mfma_f32_16x16x32_f16 %1, a[24:27], %6, %1\n\t"
            "v_mfma_f32_16x16x32_f16 %2, a[40:43], %6, %2\n\t"
            "v_mfma_f32_16x16x32_f16 %3, a[56:59], %6, %3\n\t"
            "v_mfma_f32_16x16x32_f16 %0, a[12:15], %7, %0\n\t"
            "v_mfma_f32_16x16x32_f16 %1, a[28:31], %7, %1\n\t"
            "v_mfma_f32_16x16x32_f16 %2, a[44:47], %7, %2\n\t"
            "v_mfma_f32_16x16x32_f16 %3, a[60:63], %7, %3\n\t"
            "s_nop 7\n\t"
            "s_nop 7"
            : "+&v"(di), "+&v"(df2), "+&v"(dg), "+&v"(dq)
            : "v"(b0), "v"(b1), "v"(b2), "v"(b3));
        __syncthreads();   // all h_sw reads of step t complete

        float ct = c_l[t*16 + lrow];
        unsigned int pk2 = 0x3c00u | ((unsigned int)f2h(ct) << 16);  // (1.0, ct)
        float h0, h1, h2, h3;
        CELL(0, cc0, h0) CELL(1, cc1, h1) CELL(2, cc2, h2) CELL(3, cc3, h3)

        u32x2 hpk;
        hpk[0] = (unsigned int)f2h(h0) | ((unsigned int)f2h(h1) << 16);
        hpk[1] = (unsigned int)f2h(h2) | ((unsigned int)f2h(h3) << 16);
        *(u32x2*)((char*)h_sw + hw) = hpk;
        if (dolast) lastp[t] = h3;   // j = 127
        __syncthreads();   // new h visible
    }
#undef CELL
}

// ---------------- Kernel 5: gated mean over classes + output projection
__global__ __launch_bounds__(256) void k_out(
    const float* __restrict__ lasth, const float* __restrict__ S,
    const float* __restrict__ out_w, const float* __restrict__ out_b,
    float* __restrict__ out)
{
    __shared__ __align__(16) float avg[256];
    int b = blockIdx.x, t = threadIdx.x;
    float a = 0.f;
    #pragma unroll
    for (int k = 0; k < 8; ++k) {
        // pre.reshape(NCLS,B,1): weight(k,b) = S_flat[k*64+b]
        a = fmaf(S[k * 64 + b], lasth[((size_t)k * 64 + b) * 256 + t], a);
    }
    avg[t] = a * 0.125f;
    __syncthreads();
    if (t < 8) {
        float acc = out_b[t];
        for (int tt = 0; tt < 256; ++tt)
            acc = fmaf(avg[tt], out_w[t * 256 + tt], acc);
        out[b * 8 + t] = acc;
    }
}

extern "C" void kernel_launch(void* const* d_in, const int* in_sizes, int n_in,
                              void* d_out, int out_size, void* d_ws, size_t ws_size,
                              hipStream_t stream) {
    const float* x       = (const float*)d_in[0];
    const float* conv1_w = (const float*)d_in[1];
    const float* conv1_b = (const float*)d_in[2];
    const float* bn1_g   = (const float*)d_in[3];
    const float* bn1_b   = (const float*)d_in[4];
    const float* bn1_m   = (const float*)d_in[5];
    const float* bn1_v   = (const float*)d_in[6];
    const float* conv2_w = (const float*)d_in[7];
    const float* conv2_b = (const float*)d_in[8];
    const float* bn2_g   = (const float*)d_in[9];
    const float* bn2_b   = (const float*)d_in[10];
    const float* bn2_m   = (const float*)d_in[11];
    const float* bn2_v   = (const float*)d_in[12];
    const float* pre_w1  = (const float*)d_in[13];
    const float* pre_b1  = (const float*)d_in[14];
    const float* pre_w2  = (const float*)d_in[15];
    const float* pre_b2  = (const float*)d_in[16];
    const float* pre_w3  = (const float*)d_in[17];
    const float* pre_b3  = (const float*)d_in[18];
    const float* lstm_wih = (const float*)d_in[19];
    const float* lstm_whh = (const float*)d_in[20];
    const float* lstm_bih = (const float*)d_in[21];
    const float* lstm_bhh = (const float*)d_in[22];
    const float* hn      = (const float*)d_in[23];
    const float* out_w   = (const float*)d_in[24];
    const float* out_b   = (const float*)d_in[25];

    float* ws    = (float*)d_ws;
    float* c1    = ws;                       // 64*16*64*64 = 4194304 floats
    float* c     = c1 + 4194304;             // 64*256
    float* S     = c + 16384;                // 64*8
    float* lasth = S + 512;                  // 8*64*256
    // After conv2, the c1 region is dead; reuse it for converted weights.
    unsigned int* whh_h = (unsigned int*)c1;           // 262144 u32 = 1 MB
    unsigned int* bx    = whh_h + 262144;              // 4096 u32

    k_conv1<<<1024, 256, 0, stream>>>(x, conv1_w, conv1_b, bn1_g, bn1_b, bn1_m, bn1_v, c1);
    k_conv2<<<64, 256, 0, stream>>>(c1, conv2_w, conv2_b, bn2_g, bn2_b, bn2_m, bn2_v, c);
    k_mlp<<<64, 64, 0, stream>>>(c, pre_w1, pre_b1, pre_w2, pre_b2, pre_w3, pre_b3, S);
    k_cvt<<<1024, 256, 0, stream>>>(lstm_whh, whh_h);
    k_bx<<<16, 256, 0, stream>>>(lstm_wih, lstm_bih, lstm_bhh, bx);
    k_lstm<<<32, 512, 0, stream>>>(whh_h, bx, hn, c, lasth);
    k_out<<<64, 256, 0, stream>>>(lasth, S, out_w, out_b, (float*)d_out);
}

// Round 14
// 309.615 us; speedup vs baseline: 1.5181x; 1.5181x over previous
//
#include <hip/hip_runtime.h>
#include <hip/hip_bf16.h>
#include <hip/hip_fp16.h>

// NeuralNetwork_85255100825763
// conv1+bn+relu+pool -> conv2+bn+relu+pool -> MLP+softmax gate
// -> 8x LSTM(128) over 256 steps -> gated mean -> output proj.
//
// LSTM v14 = v13 + division-free activations.
// R13 disproved the weight-reload theory: fixed-AGPR weights changed
// nothing (440us). Counters re-read: VALUBusy 9.2% GPU-wide = ~73% on the
// 32 active CUs -> VALU-throughput-bound. Cause: 4 cells/thread/step, each
// with 3 sigmoid + 2 tanh, and non-fast-math 1/(1+e) lowers to the full
// IEEE div sequence (~11 inst + ~40cy chains) -> ~3000cy/step of VALU.
// Fix: v_rcp_f32-based sigmoid/tanh (1-ULP, 1 inst) -> ~30 VALU/cell.
// Everything else identical to R13 (verified absmax 1.2e-4): weights in
// fixed AGPRs a0-a63, asm MFMA cluster, swizzled fp16 h-LDS, dot2 epilogue.

typedef _Float16 h2_t  __attribute__((ext_vector_type(2)));
typedef float    f32x4 __attribute__((ext_vector_type(4)));
typedef unsigned int u32x2 __attribute__((ext_vector_type(2)));
typedef unsigned int u32x4 __attribute__((ext_vector_type(4)));

__device__ __forceinline__ float dot2f(unsigned int w, unsigned int h, float acc) {
    return __builtin_amdgcn_fdot2(__builtin_bit_cast(h2_t, w),
                                  __builtin_bit_cast(h2_t, h), acc, false);
}
// division-free: v_rcp_f32 (~1 ULP) instead of the IEEE div sequence
__device__ __forceinline__ float sigmoidf_(float x) {
    return __builtin_amdgcn_rcpf(1.0f + __expf(-x));
}
__device__ __forceinline__ float tanhf_(float x) {
    float t = __expf(-2.0f * fabsf(x));   // in (0,1], no overflow
    float r = (1.0f - t) * __builtin_amdgcn_rcpf(1.0f + t);
    return copysignf(r, x);
}
__device__ __forceinline__ unsigned short f2h(float x) {
    __half h = __float2half(x);           // RTNE
    return *(unsigned short*)&h;
}

// ---------------- Kernel 0a: whh fp32 -> packed fp16 pairs (uint)
__global__ __launch_bounds__(256) void k_cvt(
    const float* __restrict__ w, unsigned int* __restrict__ wh)
{
    int i = blockIdx.x * 256 + threadIdx.x;     // 262144 pairs
    float2 f = ((const float2*)w)[i];
    wh[i] = (unsigned int)f2h(f.x) | ((unsigned int)f2h(f.y) << 16);
}

// ---------------- Kernel 0b: packed (bias, xw) fp16 per gate row
__global__ __launch_bounds__(256) void k_bx(
    const float* __restrict__ wih, const float* __restrict__ bih,
    const float* __restrict__ bhh, unsigned int* __restrict__ bx)
{
    int i = blockIdx.x * 256 + threadIdx.x;     // 4096 = 8*512
    float bias = bih[i] + bhh[i];
    bx[i] = (unsigned int)f2h(bias) | ((unsigned int)f2h(wih[i]) << 16);
}

// ---------------- Kernel 1: conv1 + bn1 + relu + maxpool2 -> c1 (64,16,64,64)
__global__ __launch_bounds__(256) void k_conv1(
    const float* __restrict__ x, const float* __restrict__ w,
    const float* __restrict__ cb, const float* __restrict__ g,
    const float* __restrict__ bb, const float* __restrict__ m,
    const float* __restrict__ v, float* __restrict__ c1)
{
    __shared__ __align__(16) float w1s[192];
    __shared__ float As[16], Cs[16];
    int tid = threadIdx.x;
    if (tid < 192) w1s[tid] = w[tid];
    if (tid < 16) {
        float s = g[tid] / sqrtf(v[tid] + 1e-5f);
        As[tid] = s;
        Cs[tid] = (cb[tid] - m[tid]) * s + bb[tid];
    }
    __syncthreads();

    int gid = blockIdx.x * 256 + tid;
    int b   = gid >> 12;
    int rem = gid & 4095;
    int oi  = rem >> 6, oj = rem & 63;

    float xr[3][4][4];
    #pragma unroll
    for (int ci = 0; ci < 3; ++ci) {
        #pragma unroll
        for (int r = 0; r < 4; ++r) {
            const float4 t4 = *(const float4*)(x +
                (((size_t)(b * 3 + ci) * 256 + (4 * oi + r)) * 256 + 4 * oj));
            xr[ci][r][0] = t4.x; xr[ci][r][1] = t4.y;
            xr[ci][r][2] = t4.z; xr[ci][r][3] = t4.w;
        }
    }
    const float4* w4 = (const float4*)w1s;
    #pragma unroll
    for (int co = 0; co < 16; ++co) {
        float val[2][2] = {{0.f, 0.f}, {0.f, 0.f}};
        #pragma unroll
        for (int ci = 0; ci < 3; ++ci) {
            float4 wq = w4[co * 3 + ci];
            #pragma unroll
            for (int pi = 0; pi < 2; ++pi) {
                #pragma unroll
                for (int pj = 0; pj < 2; ++pj) {
                    float a = val[pi][pj];
                    a = fmaf(xr[ci][2*pi  ][2*pj  ], wq.x, a);
                    a = fmaf(xr[ci][2*pi  ][2*pj+1], wq.y, a);
                    a = fmaf(xr[ci][2*pi+1][2*pj  ], wq.z, a);
                    a = fmaf(xr[ci][2*pi+1][2*pj+1], wq.w, a);
                    val[pi][pj] = a;
                }
            }
        }
        float A = As[co], C = Cs[co];
        float mx = 0.0f;
        #pragma unroll
        for (int pi = 0; pi < 2; ++pi)
            #pragma unroll
            for (int pj = 0; pj < 2; ++pj)
                mx = fmaxf(mx, fmaf(A, val[pi][pj], C));
        c1[((size_t)(b * 16 + co) * 64 + oi) * 64 + oj] = mx;
    }
}

// ---------------- Kernel 2: conv2 + bn2 + relu + maxpool2 -> c (64,256)
__global__ __launch_bounds__(256) void k_conv2(
    const float* __restrict__ c1, const float* __restrict__ w2,
    const float* __restrict__ cb, const float* __restrict__ g,
    const float* __restrict__ bb, const float* __restrict__ m,
    const float* __restrict__ v, float* __restrict__ c)
{
    __shared__ float w2s[64];
    int tid = threadIdx.x;
    if (tid < 64) w2s[tid] = w2[tid];
    __syncthreads();
    float A2 = g[0] / sqrtf(v[0] + 1e-5f);
    float C2 = (cb[0] - m[0]) * A2 + bb[0];

    int gid = blockIdx.x * 256 + tid;
    int b   = gid >> 8;
    int rem = gid & 255;
    int oi  = rem >> 4, oj = rem & 15;

    float val[2][2] = {{0.f, 0.f}, {0.f, 0.f}};
    for (int ci = 0; ci < 16; ++ci) {
        float xr[4][4];
        #pragma unroll
        for (int r = 0; r < 4; ++r) {
            float4 t4 = *(const float4*)(c1 +
                (((size_t)(b * 16 + ci) * 64 + (4 * oi + r)) * 64 + 4 * oj));
            xr[r][0] = t4.x; xr[r][1] = t4.y; xr[r][2] = t4.z; xr[r][3] = t4.w;
        }
        float w0 = w2s[ci*4+0], w1 = w2s[ci*4+1], w2v = w2s[ci*4+2], w3 = w2s[ci*4+3];
        #pragma unroll
        for (int pi = 0; pi < 2; ++pi) {
            #pragma unroll
            for (int pj = 0; pj < 2; ++pj) {
                float a = val[pi][pj];
                a = fmaf(xr[2*pi  ][2*pj  ], w0, a);
                a = fmaf(xr[2*pi  ][2*pj+1], w1, a);
                a = fmaf(xr[2*pi+1][2*pj  ], w2v, a);
                a = fmaf(xr[2*pi+1][2*pj+1], w3, a);
                val[pi][pj] = a;
            }
        }
    }
    float mx = 0.0f;
    #pragma unroll
    for (int pi = 0; pi < 2; ++pi)
        #pragma unroll
        for (int pj = 0; pj < 2; ++pj)
            mx = fmaxf(mx, fmaf(A2, val[pi][pj], C2));
    c[(size_t)b * 256 + oi * 16 + oj] = mx;
}

// ---------------- Kernel 3: MLP + softmax -> S (64,8) row-major flat
__global__ __launch_bounds__(64) void k_mlp(
    const float* __restrict__ c,
    const float* __restrict__ w1, const float* __restrict__ b1,
    const float* __restrict__ w2, const float* __restrict__ b2,
    const float* __restrict__ w3, const float* __restrict__ b3,
    float* __restrict__ S)
{
    __shared__ __align__(16) float cs[256];
    __shared__ float h1s[32], h2s[32], ls[8];
    int b = blockIdx.x, tid = threadIdx.x;
    *(float4*)&cs[tid * 4] = *(const float4*)(c + (size_t)b * 256 + tid * 4);
    __syncthreads();
    if (tid < 32) {
        float acc = b1[tid];
        for (int k = 0; k < 256; ++k) acc = fmaf(cs[k], w1[tid * 256 + k], acc);
        h1s[tid] = fmaxf(acc, 0.f);
    }
    __syncthreads();
    if (tid < 32) {
        float acc = b2[tid];
        #pragma unroll
        for (int k = 0; k < 32; ++k) acc = fmaf(h1s[k], w2[tid * 32 + k], acc);
        h2s[tid] = fmaxf(acc, 0.f);
    }
    __syncthreads();
    if (tid < 8) {
        float acc = b3[tid];
        #pragma unroll
        for (int k = 0; k < 32; ++k) acc = fmaf(h2s[k], w3[tid * 32 + k], acc);
        ls[tid] = acc;
    }
    __syncthreads();
    if (tid == 0) {
        float mx = ls[0];
        #pragma unroll
        for (int k = 1; k < 8; ++k) mx = fmaxf(mx, ls[k]);
        float e[8]; float sum = 0.f;
        #pragma unroll
        for (int k = 0; k < 8; ++k) { e[k] = expf(ls[k] - mx); sum += e[k]; }
        float inv = 1.0f / sum;
        #pragma unroll
        for (int k = 0; k < 8; ++k) S[b * 8 + k] = e[k] * inv;
    }
}

// write one u32x4 quad into AGPRs a<A0>..a<A0+3>
#define AWRITE4(Q, A0, A1, A2, A3)                                   \
    asm volatile("v_accvgpr_write_b32 " A0 ", %0\n\t"                \
                 "v_accvgpr_write_b32 " A1 ", %1\n\t"                \
                 "v_accvgpr_write_b32 " A2 ", %2\n\t"                \
                 "v_accvgpr_write_b32 " A3 ", %3"                    \
                 :: "v"(Q[0]), "v"(Q[1]), "v"(Q[2]), "v"(Q[3])       \
                 : A0, A1, A2, A3)

// ---------------- Kernel 4: LSTM via MFMA, weights in fixed AGPRs a0-a63.
// Block = (class, 16 batch rows), 512 threads = 8 waves.
// Wave q owns j-tile q (16 hidden dims), all 4 gate types; thread-local update.
__global__
__attribute__((amdgpu_flat_work_group_size(512, 512), amdgpu_waves_per_eu(2, 2)))
void k_lstm(
    const unsigned int* __restrict__ whh_h,  // fp16 pairs [8][512][64]
    const unsigned int* __restrict__ bx,     // packed (bias,xw) fp16 [8][512]
    const float* __restrict__ hn, const float* __restrict__ c,
    float* __restrict__ lasth)
{
    __shared__ __align__(16) unsigned short h_sw[2048];  // [16 n][128 k] fp16, byte^((n&7)<<4)
    __shared__ __align__(16) float c_l[4096];            // [256 t][16 n]

    int tid  = threadIdx.x;
    int wv   = tid >> 6, lane = tid & 63;    // wv = q = j-tile index 0..7
    int lrow = lane & 15, lgrp = lane >> 4;
    int kcls = blockIdx.x >> 2;
    int bbase = (blockIdx.x & 3) * 16;

    // ---- load 16 weight quads (transient) and park them in a0-a63 ----
    const unsigned int* wbase = whh_h + (size_t)kcls * 32768;
    int rI = (0*128 + wv*16 + lrow) * 64 + lgrp*4;
    int rF = (1*128 + wv*16 + lrow) * 64 + lgrp*4;
    int rG = (2*128 + wv*16 + lrow) * 64 + lgrp*4;
    int rO = (3*128 + wv*16 + lrow) * 64 + lgrp*4;
    {
        u32x4 q0, q1, q2, q3;
        q0 = *(const u32x4*)(wbase+rI+ 0); q1 = *(const u32x4*)(wbase+rI+16);
        q2 = *(const u32x4*)(wbase+rI+32); q3 = *(const u32x4*)(wbase+rI+48);
        AWRITE4(q0, "a0",  "a1",  "a2",  "a3");
        AWRITE4(q1, "a4",  "a5",  "a6",  "a7");
        AWRITE4(q2, "a8",  "a9",  "a10", "a11");
        AWRITE4(q3, "a12", "a13", "a14", "a15");
        q0 = *(const u32x4*)(wbase+rF+ 0); q1 = *(const u32x4*)(wbase+rF+16);
        q2 = *(const u32x4*)(wbase+rF+32); q3 = *(const u32x4*)(wbase+rF+48);
        AWRITE4(q0, "a16", "a17", "a18", "a19");
        AWRITE4(q1, "a20", "a21", "a22", "a23");
        AWRITE4(q2, "a24", "a25", "a26", "a27");
        AWRITE4(q3, "a28", "a29", "a30", "a31");
        q0 = *(const u32x4*)(wbase+rG+ 0); q1 = *(const u32x4*)(wbase+rG+16);
        q2 = *(const u32x4*)(wbase+rG+32); q3 = *(const u32x4*)(wbase+rG+48);
        AWRITE4(q0, "a32", "a33", "a34", "a35");
        AWRITE4(q1, "a36", "a37", "a38", "a39");
        AWRITE4(q2, "a40", "a41", "a42", "a43");
        AWRITE4(q3, "a44", "a45", "a46", "a47");
        q0 = *(const u32x4*)(wbase+rO+ 0); q1 = *(const u32x4*)(wbase+rO+16);
        q2 = *(const u32x4*)(wbase+rO+32); q3 = *(const u32x4*)(wbase+rO+48);
        AWRITE4(q0, "a48", "a49", "a50", "a51");
        AWRITE4(q1, "a52", "a53", "a54", "a55");
        AWRITE4(q2, "a56", "a57", "a58", "a59");
        AWRITE4(q3, "a60", "a61", "a62", "a63");
    }

    const unsigned int* bxp = bx + kcls * 512;
    u32x4 bxi = *(const u32x4*)(bxp + 0*128 + wv*16 + lgrp*4);
    u32x4 bxf = *(const u32x4*)(bxp + 1*128 + wv*16 + lgrp*4);
    u32x4 bxg = *(const u32x4*)(bxp + 2*128 + wv*16 + lgrp*4);
    u32x4 bxq = *(const u32x4*)(bxp + 3*128 + wv*16 + lgrp*4);

    #pragma unroll
    for (int i = 0; i < 2; ++i) {
        int idx = tid + i*512;
        int n = idx >> 6, j0 = (idx & 63) * 2;
        const float* hp = hn + ((size_t)kcls*64 + bbase + n)*128 + j0;
        unsigned int pk = (unsigned int)f2h(hp[0]) | ((unsigned int)f2h(hp[1]) << 16);
        *(unsigned int*)((char*)h_sw + ((n*256 + j0*2) ^ ((n & 7) << 4))) = pk;
    }
    #pragma unroll
    for (int i = 0; i < 8; ++i) {
        int idx = tid + i*512;
        int n = idx >> 8, t = idx & 255;
        c_l[t*16 + n] = c[(size_t)(bbase + n)*256 + t];
    }
    float cc0 = 0.f, cc1 = 0.f, cc2 = 0.f, cc3 = 0.f;
    __syncthreads();

    int  swz = (lrow & 7) << 4;
    int  hb  = lrow*256 + lgrp*16;
    int  hw  = (lrow*256 + (wv*16 + lgrp*4)*2) ^ swz;
    bool dolast = (wv == 7) && (lgrp == 3);         // owns j=127 (r=3)
    float* lastp = lasth + ((size_t)kcls*64 + bbase + lrow)*256;

#define CELL(R, CC, HV)                                         \
    {                                                           \
        float gi = sigmoidf_(dot2f(bxi[R], pk2, di[R]));        \
        float gf = sigmoidf_(dot2f(bxf[R], pk2, df2[R]));       \
        float gg = tanhf_   (dot2f(bxg[R], pk2, dg[R]));        \
        float go = sigmoidf_(dot2f(bxq[R], pk2, dq[R]));        \
        CC = gf * CC + gi * gg;                                 \
        HV = go * tanhf_(CC);                                   \
    }

    for (int t = 0; t < 256; ++t) {
        u32x4 b0 = *(const u32x4*)((char*)h_sw + ((hb +   0) ^ swz));
        u32x4 b1 = *(const u32x4*)((char*)h_sw + ((hb +  64) ^ swz));
        u32x4 b2 = *(const u32x4*)((char*)h_sw + ((hb + 128) ^ swz));
        u32x4 b3 = *(const u32x4*)((char*)h_sw + ((hb + 192) ^ swz));
        f32x4 di  = {0.f,0.f,0.f,0.f}, df2 = {0.f,0.f,0.f,0.f};
        f32x4 dg  = {0.f,0.f,0.f,0.f}, dq  = {0.f,0.f,0.f,0.f};
        // 16 MFMAs: A from fixed AGPRs, B/C/D in compiler VGPRs.
        asm volatile(
            "s_nop 3\n\t"
            "v_mfma_f32_16x16x32_f16 %0, a[0:3],   %4, %0\n\t"
            "v_mfma_f32_16x16x32_f16 %1, a[16:19], %4, %1\n\t"
            "v_mfma_f32_16x16x32_f16 %2, a[32:35], %4, %2\n\t"
            "v_mfma_f32_16x16x32_f16 %3, a[48:51], %4, %3\n\t"
            "v_mfma_f32_16x16x32_f16 %0, a[4:7],   %5, %0\n\t"
            "v_mfma_f32_16x16x32_f16 %1, a[20:23], %5, %1\n\t"
            "v_mfma_f32_16x16x32_f16 %2, a[36:39], %5, %2\n\t"
            "v_mfma_f32_16x16x32_f16 %3, a[52:55], %5, %3\n\t"
            "v_mfma_f32_16x16x32_f16 %0, a[8:11],  %6, %0\n\t"
            "v_mfma_f32_16x16x32_f16 %1, a[24:27], %6, %1\n\t"
            "v_mfma_f32_16x16x32_f16 %2, a[40:43], %6, %2\n\t"
            "v_mfma_f32_16x16x32_f16 %3, a[56:59], %6, %3\n\t"
            "v_mfma_f32_16x16x32_f16 %0, a[12:15], %7, %0\n\t"
            "v_mfma_f32_16x16x32_f16 %1, a[28:31], %7, %1\n\t"
            "v_mfma_f32_16x16x32_f16 %2, a[44:47], %7, %2\n\t"
            "v_mfma_f32_16x16x32_f16 %3, a[60:63], %7, %3\n\t"
            "s_nop 7\n\t"
            "s_nop 7"
            : "+&v"(di), "+&v"(df2), "+&v"(dg), "+&v"(dq)
            : "v"(b0), "v"(b1), "v"(b2), "v"(b3));
        __syncthreads();   // all h_sw reads of step t complete

        float ct = c_l[t*16 + lrow];
        unsigned int pk2 = 0x3c00u | ((unsigned int)f2h(ct) << 16);  // (1.0, ct)
        float h0, h1, h2, h3;
        CELL(0, cc0, h0) CELL(1, cc1, h1) CELL(2, cc2, h2) CELL(3, cc3, h3)

        u32x2 hpk;
        hpk[0] = (unsigned int)f2h(h0) | ((unsigned int)f2h(h1) << 16);
        hpk[1] = (unsigned int)f2h(h2) | ((unsigned int)f2h(h3) << 16);
        *(u32x2*)((char*)h_sw + hw) = hpk;
        if (dolast) lastp[t] = h3;   // j = 127
        __syncthreads();   // new h visible
    }
#undef CELL
}

// ---------------- Kernel 5: gated mean over classes + output projection
__global__ __launch_bounds__(256) void k_out(
    const float* __restrict__ lasth, const float* __restrict__ S,
    const float* __restrict__ out_w, const float* __restrict__ out_b,
    float* __restrict__ out)
{
    __shared__ __align__(16) float avg[256];
    int b = blockIdx.x, t = threadIdx.x;
    float a = 0.f;
    #pragma unroll
    for (int k = 0; k < 8; ++k) {
        // pre.reshape(NCLS,B,1): weight(k,b) = S_flat[k*64+b]
        a = fmaf(S[k * 64 + b], lasth[((size_t)k * 64 + b) * 256 + t], a);
    }
    avg[t] = a * 0.125f;
    __syncthreads();
    if (t < 8) {
        float acc = out_b[t];
        for (int tt = 0; tt < 256; ++tt)
            acc = fmaf(avg[tt], out_w[t * 256 + tt], acc);
        out[b * 8 + t] = acc;
    }
}

extern "C" void kernel_launch(void* const* d_in, const int* in_sizes, int n_in,
                              void* d_out, int out_size, void* d_ws, size_t ws_size,
                              hipStream_t stream) {
    const float* x       = (const float*)d_in[0];
    const float* conv1_w = (const float*)d_in[1];
    const float* conv1_b = (const float*)d_in[2];
    const float* bn1_g   = (const float*)d_in[3];
    const float* bn1_b   = (const float*)d_in[4];
    const float* bn1_m   = (const float*)d_in[5];
    const float* bn1_v   = (const float*)d_in[6];
    const float* conv2_w = (const float*)d_in[7];
    const float* conv2_b = (const float*)d_in[8];
    const float* bn2_g   = (const float*)d_in[9];
    const float* bn2_b   = (const float*)d_in[10];
    const float* bn2_m   = (const float*)d_in[11];
    const float* bn2_v   = (const float*)d_in[12];
    const float* pre_w1  = (const float*)d_in[13];
    const float* pre_b1  = (const float*)d_in[14];
    const float* pre_w2  = (const float*)d_in[15];
    const float* pre_b2  = (const float*)d_in[16];
    const float* pre_w3  = (const float*)d_in[17];
    const float* pre_b3  = (const float*)d_in[18];
    const float* lstm_wih = (const float*)d_in[19];
    const float* lstm_whh = (const float*)d_in[20];
    const float* lstm_bih = (const float*)d_in[21];
    const float* lstm_bhh = (const float*)d_in[22];
    const float* hn      = (const float*)d_in[23];
    const float* out_w   = (const float*)d_in[24];
    const float* out_b   = (const float*)d_in[25];

    float* ws    = (float*)d_ws;
    float* c1    = ws;                       // 64*16*64*64 = 4194304 floats
    float* c     = c1 + 4194304;             // 64*256
    float* S     = c + 16384;                // 64*8
    float* lasth = S + 512;                  // 8*64*256
    // After conv2, the c1 region is dead; reuse it for converted weights.
    unsigned int* whh_h = (unsigned int*)c1;           // 262144 u32 = 1 MB
    unsigned int* bx    = whh_h + 262144;              // 4096 u32

    k_conv1<<<1024, 256, 0, stream>>>(x, conv1_w, conv1_b, bn1_g, bn1_b, bn1_m, bn1_v, c1);
    k_conv2<<<64, 256, 0, stream>>>(c1, conv2_w, conv2_b, bn2_g, bn2_b, bn2_m, bn2_v, c);
    k_mlp<<<64, 64, 0, stream>>>(c, pre_w1, pre_b1, pre_w2, pre_b2, pre_w3, pre_b3, S);
    k_cvt<<<1024, 256, 0, stream>>>(lstm_whh, whh_h);
    k_bx<<<16, 256, 0, stream>>>(lstm_wih, lstm_bih, lstm_bhh, bx);
    k_lstm<<<32, 512, 0, stream>>>(whh_h, bx, hn, c, lasth);
    k_out<<<64, 256, 0, stream>>>(lasth, S, out_w, out_b, (float*)d_out);
}